// Round 3
// baseline (826.395 us; speedup 1.0000x reference)
//
#include <hip/hip_runtime.h>
#include <hip/hip_bf16.h>

#define N_NODES 65536
#define D_FEAT  64
#define N_EDGES 1048576
#define NBUCK   256     // buckets = row >> 8, each covers 256 rows
#define BCAP    5120    // max edges per bucket (mean 4096, sigma~64, +16 sigma)

// ---------------- Phase 1: coarse-bin edges by row>>8 ----------------
// 256 threads/block, 16 edges/thread (4096 edges/block), 256 blocks.
// Per-block LDS histogram -> one global atomic per (block,bucket) reserves a
// contiguous run -> scattered writes are ~128B contiguous runs (sector-friendly).
__global__ __launch_bounds__(256) void bin_kernel(
    const int*   __restrict__ rows,
    const int*   __restrict__ cols,
    const float* __restrict__ vals,
    int*         __restrict__ gcursor,   // [NBUCK], zeroed before launch
    uint2*       __restrict__ perm)      // [NBUCK * BCAP]
{
    __shared__ int hist[NBUCK];
    __shared__ int cur[NBUCK];
    const int tid = threadIdx.x;
    hist[tid] = 0;                       // blockDim.x == NBUCK == 256
    __syncthreads();

    const int base_e = blockIdx.x * 4096;
    int r[16];
    #pragma unroll
    for (int k = 0; k < 16; ++k) {
        r[k] = rows[base_e + k * 256 + tid];
        atomicAdd(&hist[r[k] >> 8], 1);
    }
    __syncthreads();

    // Reserve this block's run in bucket `tid`.
    cur[tid] = atomicAdd(&gcursor[tid], hist[tid]);
    __syncthreads();

    #pragma unroll
    for (int k = 0; k < 16; ++k) {
        const int e = base_e + k * 256 + tid;
        const int b = r[k] >> 8;
        const int pos = atomicAdd(&cur[b], 1);   // absolute slot within bucket
        if (pos < BCAP) {                        // statistically impossible to fail
            uint2 ent;
            ent.x = __float_as_uint(vals[e]);
            ent.y = ((unsigned)cols[e] << 8) | ((unsigned)r[k] & 255u);
            perm[(size_t)b * BCAP + pos] = ent;
        }
    }
}

// ---------------- Phase 2: one block per bucket, LDS fp32 tile ----------------
// 256-row x 64-feat tile (64KB LDS). Waves stream the bucket's edges:
// gather x[col] (coalesced 256B), ds-atomic into tile, then one coalesced store.
__global__ __launch_bounds__(1024) void bucket_spmm_kernel(
    const int*   __restrict__ gcursor,
    const uint2* __restrict__ perm,
    const float* __restrict__ x,
    float*       __restrict__ out)
{
    __shared__ float tile[256 * D_FEAT];         // 64 KB
    const int b   = blockIdx.x;
    const int tid = threadIdx.x;

    for (int i = tid; i < 256 * D_FEAT; i += 1024) tile[i] = 0.f;
    __syncthreads();

    const int cnt = min(gcursor[b], BCAP);
    const uint2* pb = perm + (size_t)b * BCAP;
    const int wave = tid >> 6;
    const int lane = tid & 63;

    int e = wave;
    for (; e + 16 < cnt; e += 32) {              // 2 gathers in flight per wave
        uint2 e0 = pb[e];
        uint2 e1 = pb[e + 16];
        float v0 = __uint_as_float(e0.x);
        float v1 = __uint_as_float(e1.x);
        int   c0 = e0.y >> 8,  r0 = e0.y & 255;
        int   c1 = e1.y >> 8,  r1 = e1.y & 255;
        float g0 = x[(size_t)c0 * D_FEAT + lane];
        float g1 = x[(size_t)c1 * D_FEAT + lane];
        atomicAdd(&tile[r0 * D_FEAT + lane], v0 * g0);
        atomicAdd(&tile[r1 * D_FEAT + lane], v1 * g1);
    }
    if (e < cnt) {
        uint2 e0 = pb[e];
        float v0 = __uint_as_float(e0.x);
        int   c0 = e0.y >> 8,  r0 = e0.y & 255;
        atomicAdd(&tile[r0 * D_FEAT + lane], v0 * x[(size_t)c0 * D_FEAT + lane]);
    }
    __syncthreads();

    float* ob = out + (size_t)b * 256 * D_FEAT;  // bucket's 64KB output slice
    for (int i = tid; i < 256 * D_FEAT; i += 1024) ob[i] = tile[i];
}

// ---------------- Fallback: round-1 atomic kernel (if ws too small) ----------------
__global__ __launch_bounds__(256) void spmm_atomic_kernel(
    const float* __restrict__ x,
    const int*   __restrict__ rows,
    const int*   __restrict__ cols,
    const float* __restrict__ vals,
    float*       __restrict__ out,
    int n_edges)
{
    const int gid  = blockIdx.x * blockDim.x + threadIdx.x;
    const int edge = gid >> 6;
    const int lane = threadIdx.x & 63;
    if (edge >= n_edges) return;
    const int   r = rows[edge];
    const int   c = cols[edge];
    const float v = vals[edge];
    atomicAdd(&out[(size_t)r * D_FEAT + lane], v * x[(size_t)c * D_FEAT + lane]);
}

extern "C" void kernel_launch(void* const* d_in, const int* in_sizes, int n_in,
                              void* d_out, int out_size, void* d_ws, size_t ws_size,
                              hipStream_t stream) {
    const float* x1      = (const float*)d_in[0];
    const float* x2      = (const float*)d_in[1];
    const int*   a1_rows = (const int*)  d_in[2];
    const int*   a1_cols = (const int*)  d_in[3];
    const float* a1_vals = (const float*)d_in[4];
    const int*   a2_rows = (const int*)  d_in[5];
    const int*   a2_cols = (const int*)  d_in[6];
    const float* a2_vals = (const float*)d_in[7];

    float* out1 = (float*)d_out;
    float* out2 = out1 + (size_t)N_NODES * D_FEAT;

    // Workspace layout: 2 cursor arrays (256 ints each), then 2 perm regions.
    int*   gcur1 = (int*)d_ws;
    int*   gcur2 = gcur1 + NBUCK;
    uint2* perm1 = (uint2*)(gcur2 + NBUCK);               // offset 2048B, 8B-aligned
    uint2* perm2 = perm1 + (size_t)NBUCK * BCAP;

    const size_t needed = 2 * NBUCK * sizeof(int)
                        + 2 * (size_t)NBUCK * BCAP * sizeof(uint2);   // ~21 MB

    if (ws_size < needed) {
        hipMemsetAsync(d_out, 0, (size_t)out_size * sizeof(float), stream);
        const int blocks = (N_EDGES * 64 + 255) / 256;
        spmm_atomic_kernel<<<blocks, 256, 0, stream>>>(x1, a1_rows, a1_cols, a1_vals, out1, N_EDGES);
        spmm_atomic_kernel<<<blocks, 256, 0, stream>>>(x2, a2_rows, a2_cols, a2_vals, out2, N_EDGES);
        return;
    }

    // Zero the bucket cursors (ws is poisoned before every call).
    hipMemsetAsync(d_ws, 0, 2 * NBUCK * sizeof(int), stream);

    bin_kernel<<<N_EDGES / 4096, 256, 0, stream>>>(a1_rows, a1_cols, a1_vals, gcur1, perm1);
    bin_kernel<<<N_EDGES / 4096, 256, 0, stream>>>(a2_rows, a2_cols, a2_vals, gcur2, perm2);

    bucket_spmm_kernel<<<NBUCK, 1024, 0, stream>>>(gcur1, perm1, x1, out1);
    bucket_spmm_kernel<<<NBUCK, 1024, 0, stream>>>(gcur2, perm2, x2, out2);
}

// Round 4
// 823.811 us; speedup vs baseline: 1.0031x; 1.0031x over previous
//
#include <hip/hip_runtime.h>
#include <hip/hip_bf16.h>

#define N_NODES 65536
#define D_FEAT  64
#define N_EDGES 1048576
#define NBUCK   512          // bucket = row >> 7 (128 rows per bucket)
#define ROWS_PB 128
#define BCAP    2560         // mean 2048, sigma ~45 -> +11 sigma headroom

// ---------------- Phase 1: coarse-bin edges by row>>7 ----------------
// 256 threads/block, 16 edges/thread (4096 edges/block), 256 blocks.
__global__ __launch_bounds__(256) void bin_kernel(
    const int*   __restrict__ rows,
    const int*   __restrict__ cols,
    const float* __restrict__ vals,
    int*         __restrict__ gcursor,   // [NBUCK], zeroed before launch
    uint2*       __restrict__ perm)      // [NBUCK * BCAP]
{
    __shared__ int hist[NBUCK];
    __shared__ int cur[NBUCK];
    const int tid = threadIdx.x;
    for (int i = tid; i < NBUCK; i += 256) hist[i] = 0;
    __syncthreads();

    const int base_e = blockIdx.x * 4096;
    int r[16];
    #pragma unroll
    for (int k = 0; k < 16; ++k) {
        r[k] = rows[base_e + k * 256 + tid];
        atomicAdd(&hist[r[k] >> 7], 1);
    }
    __syncthreads();

    for (int i = tid; i < NBUCK; i += 256)
        cur[i] = atomicAdd(&gcursor[i], hist[i]);
    __syncthreads();

    #pragma unroll
    for (int k = 0; k < 16; ++k) {
        const int e = base_e + k * 256 + tid;
        const int b = r[k] >> 7;
        const int pos = atomicAdd(&cur[b], 1);
        if (pos < BCAP) {
            uint2 ent;
            ent.x = __float_as_uint(vals[e]);
            ent.y = ((unsigned)cols[e] << 7) | ((unsigned)r[k] & 127u);
            perm[(size_t)b * BCAP + pos] = ent;
        }
    }
}

// ---------------- Phase 2: one block per bucket, LDS fp32 tile ----------------
// 512 threads = 8 waves; each wave takes 64-entry batches. Per batch: 8-entry
// unroll -> 8 independent 256B gathers in flight, then 8 fire-and-forget
// LDS atomics. Wave-uniform entry base forced scalar via readfirstlane.
__global__ __launch_bounds__(512, 4) void bucket_spmm_kernel(
    const int*   __restrict__ gcursor,
    const uint2* __restrict__ perm,
    const float* __restrict__ x,
    float*       __restrict__ out)
{
    __shared__ float tile[ROWS_PB * D_FEAT];     // 32 KB
    const int b   = blockIdx.x;
    const int tid = threadIdx.x;

    float4* t4 = (float4*)tile;
    for (int i = tid; i < ROWS_PB * D_FEAT / 4; i += 512)
        t4[i] = make_float4(0.f, 0.f, 0.f, 0.f);
    __syncthreads();

    int cnt = min(gcursor[b], BCAP);
    cnt = __builtin_amdgcn_readfirstlane(cnt);
    const uint2* pb = perm + (size_t)b * BCAP;
    const int wave = tid >> 6;
    const int lane = tid & 63;

    for (int base0 = wave * 64; base0 < cnt; base0 += 512) {
        const int base = __builtin_amdgcn_readfirstlane(base0);
        const int n = min(64, cnt - base);
        const uint2* p = pb + base;
        if (n == 64) {
            #pragma unroll
            for (int j0 = 0; j0 < 64; j0 += 8) {
                uint2 ent[8];
                #pragma unroll
                for (int k = 0; k < 8; ++k) ent[k] = p[j0 + k];
                float g[8];
                #pragma unroll
                for (int k = 0; k < 8; ++k)
                    g[k] = x[(size_t)(ent[k].y >> 7) * D_FEAT + lane];
                #pragma unroll
                for (int k = 0; k < 8; ++k)
                    atomicAdd(&tile[(ent[k].y & 127u) * D_FEAT + lane],
                              __uint_as_float(ent[k].x) * g[k]);
            }
        } else {
            for (int j = 0; j < n; ++j) {
                uint2 ent = p[j];
                atomicAdd(&tile[(ent.y & 127u) * D_FEAT + lane],
                          __uint_as_float(ent.x) *
                          x[(size_t)(ent.y >> 7) * D_FEAT + lane]);
            }
        }
    }
    __syncthreads();

    float4* ob4 = (float4*)(out + (size_t)b * ROWS_PB * D_FEAT);
    for (int i = tid; i < ROWS_PB * D_FEAT / 4; i += 512)
        ob4[i] = t4[i];
}

// ---------------- Fallback: round-1 atomic kernel (if ws too small) ----------------
__global__ __launch_bounds__(256) void spmm_atomic_kernel(
    const float* __restrict__ x,
    const int*   __restrict__ rows,
    const int*   __restrict__ cols,
    const float* __restrict__ vals,
    float*       __restrict__ out,
    int n_edges)
{
    const int gid  = blockIdx.x * blockDim.x + threadIdx.x;
    const int edge = gid >> 6;
    const int lane = threadIdx.x & 63;
    if (edge >= n_edges) return;
    const int   r = rows[edge];
    const int   c = cols[edge];
    const float v = vals[edge];
    atomicAdd(&out[(size_t)r * D_FEAT + lane], v * x[(size_t)c * D_FEAT + lane]);
}

extern "C" void kernel_launch(void* const* d_in, const int* in_sizes, int n_in,
                              void* d_out, int out_size, void* d_ws, size_t ws_size,
                              hipStream_t stream) {
    const float* x1      = (const float*)d_in[0];
    const float* x2      = (const float*)d_in[1];
    const int*   a1_rows = (const int*)  d_in[2];
    const int*   a1_cols = (const int*)  d_in[3];
    const float* a1_vals = (const float*)d_in[4];
    const int*   a2_rows = (const int*)  d_in[5];
    const int*   a2_cols = (const int*)  d_in[6];
    const float* a2_vals = (const float*)d_in[7];

    float* out1 = (float*)d_out;
    float* out2 = out1 + (size_t)N_NODES * D_FEAT;

    // Workspace: 2 cursor arrays (NBUCK ints), then 2 perm regions.
    int*   gcur1 = (int*)d_ws;
    int*   gcur2 = gcur1 + NBUCK;
    uint2* perm1 = (uint2*)(gcur2 + NBUCK);               // 8B-aligned
    uint2* perm2 = perm1 + (size_t)NBUCK * BCAP;

    const size_t needed = 2 * NBUCK * sizeof(int)
                        + 2 * (size_t)NBUCK * BCAP * sizeof(uint2);   // ~21 MB

    if (ws_size < needed) {
        hipMemsetAsync(d_out, 0, (size_t)out_size * sizeof(float), stream);
        const int blocks = (N_EDGES * 64 + 255) / 256;
        spmm_atomic_kernel<<<blocks, 256, 0, stream>>>(x1, a1_rows, a1_cols, a1_vals, out1, N_EDGES);
        spmm_atomic_kernel<<<blocks, 256, 0, stream>>>(x2, a2_rows, a2_cols, a2_vals, out2, N_EDGES);
        return;
    }

    // Zero the bucket cursors (ws is poisoned before every call).
    hipMemsetAsync(d_ws, 0, 2 * NBUCK * sizeof(int), stream);

    bin_kernel<<<N_EDGES / 4096, 256, 0, stream>>>(a1_rows, a1_cols, a1_vals, gcur1, perm1);
    bin_kernel<<<N_EDGES / 4096, 256, 0, stream>>>(a2_rows, a2_cols, a2_vals, gcur2, perm2);

    bucket_spmm_kernel<<<NBUCK, 512, 0, stream>>>(gcur1, perm1, x1, out1);
    bucket_spmm_kernel<<<NBUCK, 512, 0, stream>>>(gcur2, perm2, x2, out2);
}

// Round 6
// 226.357 us; speedup vs baseline: 3.6509x; 3.6394x over previous
//
#include <hip/hip_runtime.h>
#include <hip/hip_bf16.h>

#define N_NODES 65536
#define D_FEAT  64
#define N_EDGES 1048576
#define NBUCK   512          // bucket = row >> 7 (128 rows per bucket)
#define ROWS_PB 128
#define BCAP    2560         // mean 2048, sigma ~45 -> +11 sigma headroom

// ---------------- Phase 1: coarse-bin edges by row>>7 ----------------
// 256 threads/block, 16 edges/thread (4096 edges/block), 256 blocks.
// Per-block LDS histogram -> one global atomic per (block,bucket) reserves a
// contiguous run -> writes are short contiguous runs (sector-friendly).
__global__ __launch_bounds__(256) void bin_kernel(
    const int*   __restrict__ rows,
    const int*   __restrict__ cols,
    const float* __restrict__ vals,
    int*         __restrict__ gcursor,   // [NBUCK], zeroed before launch
    uint2*       __restrict__ perm)      // [NBUCK * BCAP]
{
    __shared__ int hist[NBUCK];
    __shared__ int cur[NBUCK];
    const int tid = threadIdx.x;
    for (int i = tid; i < NBUCK; i += 256) hist[i] = 0;
    __syncthreads();

    const int base_e = blockIdx.x * 4096;
    int r[16];
    #pragma unroll
    for (int k = 0; k < 16; ++k) {
        r[k] = rows[base_e + k * 256 + tid];
        atomicAdd(&hist[r[k] >> 7], 1);
    }
    __syncthreads();

    for (int i = tid; i < NBUCK; i += 256)
        cur[i] = atomicAdd(&gcursor[i], hist[i]);
    __syncthreads();

    #pragma unroll
    for (int k = 0; k < 16; ++k) {
        const int e = base_e + k * 256 + tid;
        const int b = r[k] >> 7;
        const int pos = atomicAdd(&cur[b], 1);
        if (pos < BCAP) {
            uint2 ent;
            ent.x = __float_as_uint(vals[e]);
            ent.y = ((unsigned)cols[e] << 7) | ((unsigned)r[k] & 127u);
            perm[(size_t)b * BCAP + pos] = ent;
        }
    }
}

// ---------------- Phase 2: fused in-LDS counting-sort + CSR SpMM ----------------
// One 1024-thread block per bucket. Entries sorted by row&127 inside LDS,
// then each wave register-accumulates 8 rows (CSR-style, no atomics anywhere).
__global__ __launch_bounds__(1024, 4) void bucket_sort_spmm_kernel(
    const int*   __restrict__ gcursor,
    const uint2* __restrict__ perm,
    const float* __restrict__ x,
    float*       __restrict__ out)
{
    __shared__ uint2 ent[BCAP];            // 20 KB
    __shared__ int   hist[ROWS_PB];
    __shared__ int   offs[ROWS_PB + 1];
    __shared__ int   cur[ROWS_PB];
    __shared__ int   stmp[ROWS_PB];

    const int b   = blockIdx.x;
    const int tid = threadIdx.x;
    const int cnt = min(gcursor[b], BCAP);

    if (tid < ROWS_PB) hist[tid] = 0;
    __syncthreads();

    // Load up to 3 entries/thread into registers; histogram row bins.
    uint2 mine[3];
    int nm = 0;
    for (int i = tid; i < cnt; i += 1024) {
        uint2 e = perm[(size_t)b * BCAP + i];
        mine[nm++] = e;
        atomicAdd(&hist[e.y & (ROWS_PB - 1)], 1);
    }
    __syncthreads();

    // Exclusive scan of the 128 bins (Hillis-Steele on threads 0..127).
    if (tid < ROWS_PB) stmp[tid] = hist[tid];
    __syncthreads();
    for (int off = 1; off < ROWS_PB; off <<= 1) {
        int v = 0;
        if (tid < ROWS_PB && tid >= off) v = stmp[tid - off];
        __syncthreads();
        if (tid < ROWS_PB) stmp[tid] += v;
        __syncthreads();
    }
    if (tid < ROWS_PB) {
        int excl = stmp[tid] - hist[tid];
        offs[tid] = excl;
        cur[tid]  = excl;
    }
    if (tid == 0) offs[ROWS_PB] = cnt;
    __syncthreads();

    // Scatter registers into row-sorted LDS order.
    for (int k = 0; k < nm; ++k) {
        int r   = mine[k].y & (ROWS_PB - 1);
        int pos = atomicAdd(&cur[r], 1);
        ent[pos] = mine[k];
    }
    __syncthreads();

    // CSR-style SpMM: wave w owns rows w*8 .. w*8+7, register accumulate.
    const int wave = tid >> 6;
    const int lane = tid & 63;
    float* ob = out + (size_t)b * ROWS_PB * D_FEAT;

    #pragma unroll
    for (int rr = 0; rr < 8; ++rr) {
        const int r   = wave * 8 + rr;
        int e         = offs[r];
        const int end = offs[r + 1];
        float acc = 0.f;

        for (; e + 3 < end; e += 4) {          // 4 independent gathers in flight
            uint2 e0 = ent[e],     e1 = ent[e + 1];
            uint2 e2 = ent[e + 2], e3 = ent[e + 3];
            float g0 = x[(size_t)(e0.y >> 7) * D_FEAT + lane];
            float g1 = x[(size_t)(e1.y >> 7) * D_FEAT + lane];
            float g2 = x[(size_t)(e2.y >> 7) * D_FEAT + lane];
            float g3 = x[(size_t)(e3.y >> 7) * D_FEAT + lane];
            acc = fmaf(__uint_as_float(e0.x), g0, acc);
            acc = fmaf(__uint_as_float(e1.x), g1, acc);
            acc = fmaf(__uint_as_float(e2.x), g2, acc);
            acc = fmaf(__uint_as_float(e3.x), g3, acc);
        }
        for (; e < end; ++e) {
            uint2 e0 = ent[e];
            acc = fmaf(__uint_as_float(e0.x),
                       x[(size_t)(e0.y >> 7) * D_FEAT + lane], acc);
        }
        ob[(size_t)r * D_FEAT + lane] = acc;   // coalesced 256B store per row
    }
}

// ---------------- Fallback: round-1 atomic kernel (if ws too small) ----------------
__global__ __launch_bounds__(256) void spmm_atomic_kernel(
    const float* __restrict__ x,
    const int*   __restrict__ rows,
    const int*   __restrict__ cols,
    const float* __restrict__ vals,
    float*       __restrict__ out,
    int n_edges)
{
    const int gid  = blockIdx.x * blockDim.x + threadIdx.x;
    const int edge = gid >> 6;
    const int lane = threadIdx.x & 63;
    if (edge >= n_edges) return;
    const int   r = rows[edge];
    const int   c = cols[edge];
    const float v = vals[edge];
    atomicAdd(&out[(size_t)r * D_FEAT + lane], v * x[(size_t)c * D_FEAT + lane]);
}

extern "C" void kernel_launch(void* const* d_in, const int* in_sizes, int n_in,
                              void* d_out, int out_size, void* d_ws, size_t ws_size,
                              hipStream_t stream) {
    const float* x1      = (const float*)d_in[0];
    const float* x2      = (const float*)d_in[1];
    const int*   a1_rows = (const int*)  d_in[2];
    const int*   a1_cols = (const int*)  d_in[3];
    const float* a1_vals = (const float*)d_in[4];
    const int*   a2_rows = (const int*)  d_in[5];
    const int*   a2_cols = (const int*)  d_in[6];
    const float* a2_vals = (const float*)d_in[7];

    float* out1 = (float*)d_out;
    float* out2 = out1 + (size_t)N_NODES * D_FEAT;

    // Workspace: 2 cursor arrays (NBUCK ints), then 2 perm regions.
    int*   gcur1 = (int*)d_ws;
    int*   gcur2 = gcur1 + NBUCK;
    uint2* perm1 = (uint2*)(gcur2 + NBUCK);               // 8B-aligned
    uint2* perm2 = perm1 + (size_t)NBUCK * BCAP;

    const size_t needed = 2 * NBUCK * sizeof(int)
                        + 2 * (size_t)NBUCK * BCAP * sizeof(uint2);   // ~21 MB

    if (ws_size < needed) {
        hipMemsetAsync(d_out, 0, (size_t)out_size * sizeof(float), stream);
        const int blocks = (N_EDGES * 64 + 255) / 256;
        spmm_atomic_kernel<<<blocks, 256, 0, stream>>>(x1, a1_rows, a1_cols, a1_vals, out1, N_EDGES);
        spmm_atomic_kernel<<<blocks, 256, 0, stream>>>(x2, a2_rows, a2_cols, a2_vals, out2, N_EDGES);
        return;
    }

    // Zero the bucket cursors (ws is poisoned before every call).
    hipMemsetAsync(d_ws, 0, 2 * NBUCK * sizeof(int), stream);

    bin_kernel<<<N_EDGES / 4096, 256, 0, stream>>>(a1_rows, a1_cols, a1_vals, gcur1, perm1);
    bin_kernel<<<N_EDGES / 4096, 256, 0, stream>>>(a2_rows, a2_cols, a2_vals, gcur2, perm2);

    bucket_sort_spmm_kernel<<<NBUCK, 1024, 0, stream>>>(gcur1, perm1, x1, out1);
    bucket_sort_spmm_kernel<<<NBUCK, 1024, 0, stream>>>(gcur2, perm2, x2, out2);
}